// Round 3
// baseline (155.829 us; speedup 1.0000x reference)
//
#include <hip/hip_runtime.h>
#include <hip/hip_bf16.h>
#include <math.h>

#define B_ 4
#define N_ 256
#define D_ 128
#define H_ 256
#define K_ 8
#define DC8 8

typedef __attribute__((ext_vector_type(8))) short short8;
typedef __attribute__((ext_vector_type(4))) float f32x4;

__device__ __forceinline__ unsigned short f2bf(float x) {
    union { __hip_bfloat16 h; unsigned short s; } u;
    u.h = __float2bfloat16(x);
    return u.s;
}
__device__ __forceinline__ unsigned pk2(float x, float y) {
    union { __hip_bfloat162 h; unsigned u; } c;
    c.h = __float22bfloat162_rn(float2{x, y});
    return c.u;
}
// async global->LDS, 16 B per lane; no VGPR round-trip
__device__ __forceinline__ void gld_lds16(const float* g, float* l) {
    __builtin_amdgcn_global_load_lds(
        (const __attribute__((address_space(1))) void*)g,
        (__attribute__((address_space(3))) void*)l, 16, 0, 0);
}

// K0 (unchanged, proven): avec = W1a*s_i + b1, bvec = W1b*s_j, Wt = W1c^T bf16.
__global__ __launch_bounds__(256) void pre_kernel(
    const float* __restrict__ s, const float* __restrict__ W1,
    const float* __restrict__ b1,
    float* __restrict__ avec, float* __restrict__ bvec,
    unsigned short* __restrict__ Wt)
{
    int blk = blockIdx.x;
    int t = threadIdx.x;
    if (blk < 512) {
        int bi0 = blk * 2;
        __shared__ float s2[2][D_];
        {
            int r = t >> 7, d = t & 127;
            s2[r][d] = s[(size_t)(bi0 + r) * D_ + d];
        }
        __syncthreads();
        float aA0 = b1[t], aA1 = aA0, aB0 = 0.f, aB1 = 0.f;
        const float* W1a = W1 + t;
        const float* W1b = W1 + (size_t)D_ * H_ + t;
        #pragma unroll 8
        for (int d = 0; d < D_; ++d) {
            float wa = W1a[(size_t)d * H_];
            float wb = W1b[(size_t)d * H_];
            float s0 = s2[0][d], s1 = s2[1][d];
            aA0 = fmaf(s0, wa, aA0);
            aA1 = fmaf(s1, wa, aA1);
            aB0 = fmaf(s0, wb, aB0);
            aB1 = fmaf(s1, wb, aB1);
        }
        avec[(size_t)bi0 * H_ + t]       = aA0;
        avec[(size_t)(bi0 + 1) * H_ + t] = aA1;
        bvec[(size_t)bi0 * H_ + t]       = aB0;
        bvec[(size_t)(bi0 + 1) * H_ + t] = aB1;
    } else {
        int e = (blk - 512) * 256 + t;
        int h = e >> 7, d = e & 127;
        Wt[e] = f2bf(W1[(size_t)(2 * D_ + d) * H_ + h]);
    }
}

// Mega-kernel: block = 2 rows x ALL 256 j. Phase 1: 16 rounds (2 i x 8
// j-tiles) of the proven MFMA score pipeline -> full fp32 score rows in
// LDS (no ascu global round-trip, no bf16 output rounding). Phase 2: the
// proven finalize logic (top-16 -> exact fp32 rescore -> top-8 -> outputs)
// in the SAME block after __syncthreads — dependency is block-local, so no
// grid sync and no third launch. LDS ~36 KB -> 2 blocks/CU @ 512 thr.
__global__ __launch_bounds__(512, 2) void mega_kernel(
    const float* __restrict__ s, const unsigned short* __restrict__ Wt,
    const float* __restrict__ W1, const float* __restrict__ W2,
    const float* __restrict__ b2,
    const float* __restrict__ avec, const float* __restrict__ bvec,
    float* __restrict__ ctx, float* __restrict__ gate,
    float* __restrict__ wout)
{
    int blk = blockIdx.x;              // 512 blocks, 2 global rows each
    int bi0 = blk * 2;
    int b   = blk >> 7;
    int t = threadIdx.x;
    int lane = t & 63;
    int wq = __builtin_amdgcn_readfirstlane(t >> 6);   // wave 0..7 -> 32-h slice
    int l15 = lane & 15, quad = lane >> 4;
    int prow = t >> 4, pseg = t & 15;                  // P-build mapping

    __shared__ float asc[2][N_];                       // 2 KB, persists ph1->ph2
    union U {
        struct {                                       // phase 1 (~19.5 KB)
            short Pl[2][32 * 128];                     // 16 KB dbuf
            float si2[2][D_];                          // 1 KB (own 2 rows)
            float partial[2][8][32];                   // 2 KB
        } p;
        struct {                                       // phase 2 (~34 KB)
            float Pt[D_ * 32];                         // 16 KB
            float Wl[2][DC8 * H_];                     // 16 KB DMA dbuf
            float partW[8][2][16];                     // 1 KB
            float rsc[2][16];
            int   cand[2][16];
            int   sel8[2][8];
        } c;
    };
    __shared__ __align__(16) U sm;

    const float* sB = s + (size_t)b * N_ * D_;

    // own 2 rows of s -> LDS (read by P-build every round)
    if (t < 256) {
        int r = t >> 7, d = t & 127;
        sm.p.si2[r][d] = s[(size_t)(bi0 + r) * D_ + d];
    }

    // hoists: Wt fragments, W2, avec for own 2 rows, b2
    short8 Wreg[2][4];
    #pragma unroll
    for (int mi = 0; mi < 2; ++mi)
        #pragma unroll
        for (int dk = 0; dk < 4; ++dk)
            Wreg[mi][dk] = *(const short8*)(
                Wt + (size_t)(wq * 32 + mi * 16 + l15) * D_ + dk * 32 + quad * 8);
    float w2r[2][4];
    float4 av4[2][2];
    #pragma unroll
    for (int mi = 0; mi < 2; ++mi) {
        int hq = wq * 32 + mi * 16 + quad * 4;
        #pragma unroll
        for (int r = 0; r < 4; ++r)
            w2r[mi][r] = W2[hq + r];
        #pragma unroll
        for (int ir = 0; ir < 2; ++ir)
            av4[ir][mi] = *(const float4*)&avec[(size_t)(bi0 + ir) * H_ + hq];
    }
    float b2v = b2[0];
    __syncthreads();                   // si2 ready

    // P-build round 0 (ir=0, jt=0)
    {
        const float* sj = sB + (size_t)(0 * 32 + prow) * D_ + pseg * 8;
        float4 a0 = ((const float4*)sj)[0], a1 = ((const float4*)sj)[1];
        const float* si = &sm.p.si2[0][pseg * 8];
        float4 s0 = ((const float4*)si)[0], s1 = ((const float4*)si)[1];
        uint4 v;
        v.x = pk2(a0.x * s0.x, a0.y * s0.y);
        v.y = pk2(a0.z * s0.z, a0.w * s0.w);
        v.z = pk2(a1.x * s1.x, a1.y * s1.y);
        v.w = pk2(a1.z * s1.z, a1.w * s1.w);
        int pc = pseg ^ (prow & 15);
        *(uint4*)&sm.p.Pl[0][prow * 128 + pc * 8] = v;
    }
    __syncthreads();

    // ---- 16 rounds: r = ir*8 + jt ----
    #pragma unroll 1
    for (int r = 0; r < 16; ++r) {
        int cur = r & 1;
        int ir = r >> 3, jt = r & 7;
        if (wq == 0 && lane < 32 && r > 0) {
            int pr = r - 1;
            float sum = b2v;
            #pragma unroll
            for (int ww = 0; ww < 8; ++ww)
                sum += sm.p.partial[pr & 1][ww][lane];
            asc[pr >> 3][(pr & 7) * 32 + lane] = sum;
        }
        // bias for this j-tile: issued now, consumed in epilogue (hidden by MFMA)
        float4 bv4[2][2];
        #pragma unroll
        for (int mi = 0; mi < 2; ++mi)
            #pragma unroll
            for (int nj = 0; nj < 2; ++nj)
                bv4[mi][nj] = *(const float4*)&bvec[
                    ((size_t)(b * N_ + jt * 32 + nj * 16 + l15)) * H_
                    + wq * 32 + mi * 16 + quad * 4];
        // C-init = a_i[h] (register, no latency)
        f32x4 acc[2][2];
        #pragma unroll
        for (int mi = 0; mi < 2; ++mi)
            #pragma unroll
            for (int nj = 0; nj < 2; ++nj)
                #pragma unroll
                for (int rx = 0; rx < 4; ++rx)
                    acc[mi][nj][rx] = av4[ir][mi][rx];
        #pragma unroll
        for (int dk = 0; dk < 4; ++dk) {
            short8 Pf[2];
            #pragma unroll
            for (int nj = 0; nj < 2; ++nj) {
                int pcc = (dk * 4 + quad) ^ l15;
                Pf[nj] = *(const short8*)&sm.p.Pl[cur][(nj * 16 + l15) * 128 + pcc * 8];
            }
            #pragma unroll
            for (int nj = 0; nj < 2; ++nj)
                #pragma unroll
                for (int mi = 0; mi < 2; ++mi)
                    acc[mi][nj] = __builtin_amdgcn_mfma_f32_16x16x32_bf16(
                        Wreg[mi][dk], Pf[nj], acc[mi][nj], 0, 0, 0);
        }
        if (r < 15) {                  // P-build round r+1
            int nr = r + 1;
            int ir2 = nr >> 3, jt2 = nr & 7;
            const float* sj = sB + (size_t)(jt2 * 32 + prow) * D_ + pseg * 8;
            float4 a0 = ((const float4*)sj)[0], a1 = ((const float4*)sj)[1];
            const float* si = &sm.p.si2[ir2][pseg * 8];
            float4 s0 = ((const float4*)si)[0], s1 = ((const float4*)si)[1];
            uint4 v;
            v.x = pk2(a0.x * s0.x, a0.y * s0.y);
            v.y = pk2(a0.z * s0.z, a0.w * s0.w);
            v.z = pk2(a1.x * s1.x, a1.y * s1.y);
            v.w = pk2(a1.z * s1.z, a1.w * s1.w);
            int pc = pseg ^ (prow & 15);
            *(uint4*)&sm.p.Pl[cur ^ 1][prow * 128 + pc * 8] = v;
        }
        float rs[2];
        rs[0] = 0.f; rs[1] = 0.f;
        #pragma unroll
        for (int mi = 0; mi < 2; ++mi)
            #pragma unroll
            for (int nj = 0; nj < 2; ++nj)
                #pragma unroll
                for (int rx = 0; rx < 4; ++rx) {
                    float z = acc[mi][nj][rx] + bv4[mi][nj][rx];
                    rs[nj] = fmaf(fmaxf(z, 0.f), w2r[mi][rx], rs[nj]);
                }
        #pragma unroll
        for (int nj = 0; nj < 2; ++nj) {
            rs[nj] += __shfl_xor(rs[nj], 16);
            rs[nj] += __shfl_xor(rs[nj], 32);
        }
        if (lane < 32) {
            float v = (quad == 0) ? rs[0] : rs[1];
            sm.p.partial[cur][wq][lane] = v;
        }
        __syncthreads();
    }
    if (wq == 0 && lane < 32) {        // round-15 gather
        float sum = b2v;
        #pragma unroll
        for (int ww = 0; ww < 8; ++ww)
            sum += sm.p.partial[1][ww][lane];
        asc[1][7 * 32 + lane] = sum;
    }
    __syncthreads();                   // asc complete; ph1 LDS dead

    // ================= phase 2: finalize (block-local) =================
    // rank-select top-16: 1 j per thread (fp32 scores, tiebreak low index)
    {
        int r2 = t >> 8, lj = t & 255;
        float my = asc[r2][lj]; int rk = 0;
        #pragma unroll 4
        for (int j2 = 0; j2 < N_; ++j2) {
            float o = asc[r2][j2];
            rk += (o > my) || (o == my && j2 < lj);
        }
        if (rk < 16) sm.c.cand[r2][rk] = lj;
    }
    __syncthreads();

    const float* Wc = W1 + (size_t)2 * D_ * H_;        // W1c[d][h]

    // async DMA of W chunk 0 (8 KB = 512 x 16 B; 1 slot/thread)
    gld_lds16(Wc + t * 4, &sm.c.Wl[0][0] + t * 4);

    // build Pt: Pt[d*32 + rr*16 + c] = s_i[d]*s_j[d]
    for (int e = t; e < 1024; e += 512) {
        int rr = e >> 9, c = e & 15, dq = (e >> 4) & 31;
        int j = sm.c.cand[rr][c];
        float4 sj = *(const float4*)(s + ((size_t)(b * N_ + j)) * D_ + dq * 4);
        float4 si = *(const float4*)(s + ((size_t)(bi0 + rr)) * D_ + dq * 4);
        int base = (dq * 4) * 32 + rr * 16 + c;
        sm.c.Pt[base + 0 * 32] = si.x * sj.x;
        sm.c.Pt[base + 1 * 32] = si.y * sj.y;
        sm.c.Pt[base + 2 * 32] = si.z * sj.z;
        sm.c.Pt[base + 3 * 32] = si.w * sj.w;
    }

    // acc init: exact fp32 a_i[h] + b_j[h] for 2 cands x 8 h
    int cg2 = t & 7, rr = (t >> 3) & 1, hg = t >> 4;   // hg 0..31
    int h0 = hg * 8;
    float facc[2][8];
    {
        const float* av = avec + (size_t)(bi0 + rr) * H_ + h0;
        float4 av40 = *(const float4*)(av);
        float4 av41 = *(const float4*)(av + 4);
        #pragma unroll
        for (int cc = 0; cc < 2; ++cc) {
            int j = sm.c.cand[rr][cg2 * 2 + cc];
            const float* bv = bvec + ((size_t)(b * N_ + j)) * H_ + h0;
            float4 b40 = *(const float4*)(bv);
            float4 b41 = *(const float4*)(bv + 4);
            facc[cc][0] = av40.x + b40.x;
            facc[cc][1] = av40.y + b40.y;
            facc[cc][2] = av40.z + b40.z;
            facc[cc][3] = av40.w + b40.w;
            facc[cc][4] = av41.x + b41.x;
            facc[cc][5] = av41.y + b41.y;
            facc[cc][6] = av41.z + b41.z;
            facc[cc][7] = av41.w + b41.w;
        }
    }
    __syncthreads();   // drains chunk-0 DMA + Pt writes

    // K-chunked exact GEMM (16 chunks of 8 d), async double-buffered W
    int pvoff = rr * 16 + cg2 * 2;
    #pragma unroll 1
    for (int ch = 0; ch < 16; ++ch) {
        int cur = ch & 1;
        if (ch < 15)
            gld_lds16(Wc + (size_t)(ch + 1) * DC8 * H_ + t * 4,
                      &sm.c.Wl[cur ^ 1][0] + t * 4);
        int d0 = ch * DC8;
        #pragma unroll
        for (int d = 0; d < DC8; ++d) {
            float2 pv = *(const float2*)&sm.c.Pt[(d0 + d) * 32 + pvoff];
            float wv[8];
            *(float4*)&wv[0] = *(const float4*)&sm.c.Wl[cur][d * H_ + h0];
            *(float4*)&wv[4] = *(const float4*)&sm.c.Wl[cur][d * H_ + h0 + 4];
            #pragma unroll
            for (int m = 0; m < 8; ++m) {
                facc[0][m] = fmaf(pv.x, wv[m], facc[0][m]);
                facc[1][m] = fmaf(pv.y, wv[m], facc[1][m]);
            }
        }
        __syncthreads();
    }

    // epilogue: relu * W2, wave-shuffle reduce (lanes l, l^16, l^32, l^48
    // share (cg2, rr)), then sum 8 per-wave partials
    {
        float w2v[8];
        *(float4*)&w2v[0] = *(const float4*)(W2 + h0);
        *(float4*)&w2v[4] = *(const float4*)(W2 + h0 + 4);
        int wv_id = t >> 6;
        #pragma unroll
        for (int cc = 0; cc < 2; ++cc) {
            float sc = 0.f;
            #pragma unroll
            for (int m = 0; m < 8; ++m)
                sc = fmaf(fmaxf(facc[cc][m], 0.f), w2v[m], sc);
            sc += __shfl_xor(sc, 16);
            sc += __shfl_xor(sc, 32);
            if (lane < 16) sm.c.partW[wv_id][rr][cg2 * 2 + cc] = sc;
        }
    }
    __syncthreads();
    if (t < 32) {
        int r2 = t >> 4, c2 = t & 15;
        float sum = b2v;
        #pragma unroll
        for (int wv2 = 0; wv2 < 8; ++wv2) sum += sm.c.partW[wv2][r2][c2];
        sm.c.rsc[r2][c2] = sum;
    }
    __syncthreads();

    // top-8 among 16 exact scores, tiebreak smaller original index
    if (t < 32) {
        int r2 = t >> 4, c2 = t & 15;
        float my = sm.c.rsc[r2][c2]; int myj = sm.c.cand[r2][c2];
        int rank = 0;
        #pragma unroll
        for (int c3 = 0; c3 < 16; ++c3) {
            float o = sm.c.rsc[r2][c3]; int oj = sm.c.cand[r2][c3];
            rank += (o > my) || (o == my && oj < myj);
        }
        if (rank < 8) sm.c.sel8[r2][rank] = myj;
    }
    __syncthreads();

    // gate / w: 1 per thread
    {
        int r2 = t >> 8, jj = t & 255;
        float gv = 0.f;
        #pragma unroll
        for (int m = 0; m < 8; ++m)
            gv = (jj == sm.c.sel8[r2][m]) ? 1.f : gv;
        gate[(size_t)(bi0 + r2) * N_ + jj] = gv;
        wout[(size_t)(bi0 + r2) * N_ + jj] = gv * 0.125f;
    }
    // ctx: 2 rows x 128 d
    if (t < 256) {
        int r2 = t >> 7, d = t & 127;
        float a = 0.f;
        #pragma unroll
        for (int m = 0; m < 8; ++m)
            a += s[((size_t)(b * N_ + sm.c.sel8[r2][m])) * D_ + d];
        ctx[(size_t)(bi0 + r2) * D_ + d] = a * 0.125f;
    }
}

extern "C" void kernel_launch(void* const* d_in, const int* in_sizes, int n_in,
                              void* d_out, int out_size, void* d_ws, size_t ws_size,
                              hipStream_t stream)
{
    const float* s  = (const float*)d_in[0];
    const float* W1 = (const float*)d_in[1];
    const float* b1 = (const float*)d_in[2];
    const float* W2 = (const float*)d_in[3];
    const float* b2 = (const float*)d_in[4];

    float* avec = (float*)d_ws;                                           // 262144 f
    float* bvec = avec + (size_t)B_ * N_ * H_;                            // 262144 f
    unsigned short* Wtu = (unsigned short*)(bvec + (size_t)B_ * N_ * H_); // 32768 us

    float* ctx  = (float*)d_out;
    float* gate = ctx + (size_t)B_ * N_ * D_;
    float* wout = gate + (size_t)B_ * N_ * N_;

    pre_kernel<<<640, 256, 0, stream>>>(s, W1, b1, avec, bvec, Wtu);
    mega_kernel<<<512, 512, 0, stream>>>(s, Wtu, W1, W2, b2, avec, bvec,
                                         ctx, gate, wout);
}